// Round 1
// baseline (399.444 us; speedup 1.0000x reference)
//
#include <hip/hip_runtime.h>
#include <hip/hip_bf16.h>

// Problem constants
#define NB    8
#define SQN   2048
#define SKN   4096
#define DDIM  512
#define DVDIM 256
#define NROWS (NB*SQN)      // 16384
#define NS    2             // SK splits
#define NJ    ((SKN/64)/NS) // 32 j-iterations per split (64 keys each)

typedef __attribute__((ext_vector_type(8)))  short bf16x8;   // 8 bf16 = 4 VGPRs (MFMA A/B frag)
typedef __attribute__((ext_vector_type(4)))  short bf16x4;
typedef __attribute__((ext_vector_type(4)))  float f32x4;    // 16x16 MFMA C/D frag
typedef __attribute__((ext_vector_type(16))) float f32x16;   // 32x32 MFMA C/D frag

// fp32 -> bf16 round-to-nearest-even, bit pattern as short
__device__ __forceinline__ short f2bf(float f) {
    unsigned u = __float_as_uint(f);
    return (short)((u + 0x7FFFu + ((u >> 16) & 1u)) >> 16);
}

// async global->LDS, 16B per lane; LDS dst = wave-uniform base + lane*16,
// global src may be per-lane (used for read-side swizzle)
__device__ __forceinline__ void gload_lds16(const void* g, void* l) {
    __builtin_amdgcn_global_load_lds(
        (const __attribute__((address_space(1))) unsigned int*)g,
        (__attribute__((address_space(3))) unsigned int*)l, 16, 0, 0);
}

// ---------------------------------------------------------------------------
// Fused projection GEMMs, one launch. grid = (64, 8, 2).  (unchanged)
//  z=0: key[s][d]  = sum_c Y[s][c]*Wk[d][c]   M=4096 N=512
//  z=1: vt[dv][s]  = sum_c Wv[dv][c]*Z[s][c]  M=256  N=4096 (uses 256 of 512 tiles)
// ---------------------------------------------------------------------------
__global__ __launch_bounds__(256, 2) void proj_gemms(
    const float* __restrict__ Y, const float* __restrict__ Z,
    const float* __restrict__ Wk, const float* __restrict__ Wv,
    unsigned short* __restrict__ keyb, unsigned short* __restrict__ vtb)
{
    __shared__ short sA[64*128];   // 16 KB
    __shared__ short sB[64*128];   // 16 KB
    const float *A, *Bm;
    unsigned short* C;
    int N, m0, n0;
    if (blockIdx.z == 0) {
        A = Y; Bm = Wk; C = keyb; N = DDIM;
        m0 = blockIdx.x * 64; n0 = blockIdx.y * 64;
    } else {
        int lin = blockIdx.x * 8 + blockIdx.y;
        if (lin >= 256) return;                 // value GEMM needs 256 tiles
        A = Wv; Bm = Z; C = vtb; N = SKN;
        m0 = (lin >> 6) * 64; n0 = (lin & 63) * 64;
    }
    const int tid  = threadIdx.x;
    const int wave = tid >> 6;
    const int lane = tid & 63;
    const int quad = lane >> 4;
    const int l15  = lane & 15;

    f32x4 acc[4];
    #pragma unroll
    for (int n = 0; n < 4; ++n) { acc[n][0]=0.f; acc[n][1]=0.f; acc[n][2]=0.f; acc[n][3]=0.f; }

    float4 ra[8], rb[8];
    #pragma unroll
    for (int it = 0; it < 8; ++it) {            // prefetch kc=0
        int f = it*1024 + tid*4, row = f >> 7, col = f & 127;
        ra[it] = *(const float4*)(A  + (size_t)(m0+row)*DDIM + col);
        rb[it] = *(const float4*)(Bm + (size_t)(n0+row)*DDIM + col);
    }

    for (int kc = 0; kc < DDIM; kc += 128) {
        __syncthreads();                        // LDS free (prev MFMA done)
        #pragma unroll
        for (int it = 0; it < 8; ++it) {
            int f = it*1024 + tid*4;
            bf16x4 a4; a4[0]=f2bf(ra[it].x); a4[1]=f2bf(ra[it].y); a4[2]=f2bf(ra[it].z); a4[3]=f2bf(ra[it].w);
            *(bf16x4*)(sA + f) = a4;
            bf16x4 b4; b4[0]=f2bf(rb[it].x); b4[1]=f2bf(rb[it].y); b4[2]=f2bf(rb[it].z); b4[3]=f2bf(rb[it].w);
            *(bf16x4*)(sB + f) = b4;
        }
        __syncthreads();                        // staged visible
        if (kc + 128 < DDIM) {                  // prefetch kc+1 (in flight under MFMA)
            #pragma unroll
            for (int it = 0; it < 8; ++it) {
                int f = it*1024 + tid*4, row = f >> 7, col = f & 127;
                ra[it] = *(const float4*)(A  + (size_t)(m0+row)*DDIM + kc + 128 + col);
                rb[it] = *(const float4*)(Bm + (size_t)(n0+row)*DDIM + kc + 128 + col);
            }
        }
        #pragma unroll
        for (int t = 0; t < 4; ++t) {
            bf16x8 af = *(const bf16x8*)(sA + (wave*16 + l15)*128 + t*32 + quad*8);
            #pragma unroll
            for (int n = 0; n < 4; ++n) {
                bf16x8 bfr = *(const bf16x8*)(sB + (n*16 + l15)*128 + t*32 + quad*8);
                acc[n] = __builtin_amdgcn_mfma_f32_16x16x32_bf16(af, bfr, acc[n], 0, 0, 0);
            }
        }
    }
    #pragma unroll
    for (int n = 0; n < 4; ++n)
        #pragma unroll
        for (int r = 0; r < 4; ++r) {
            int m  = m0 + wave*16 + quad*4 + r;
            int nn = n0 + n*16 + l15;
            C[(size_t)m*N + nn] = (unsigned short)f2bf(acc[n][r]);
        }
}

// ---------------------------------------------------------------------------
// Fused attention, 32x32x16 swapped-operand restructure.
// grid = (NROWS/64, NS), block = 256 = 4 waves as 2x2:
//   wm = wave>>1 selects Q rows [q0 + wm*32, +32); wk = wave&1 selects the
//   32-key half of each 64-key j-tile. Each wave runs an INDEPENDENT online
//   softmax over its 1024-key stripe; the two wk halves are merged in-kernel
//   at the epilogue (same math as combine_splits). Workspace/grid unchanged.
// Why: R6 diagnosis — kernel is LDS-BW-bound (504 KB/block/j) + softmax
// shuffle chains. 32x32 frags halve LDS bytes/FLOP; swapped QK^T
// (mfma(K,Q)) makes P^T lane-local -> softmax is in-lane (1 shfl_xor(32)),
// and P feeds PV directly from registers via cvt_pk + permlane32_swap
// (no sP round-trip). LDS traffic per block/j: 504 -> ~288 KB.
// Same proven 4-barrier/j pipeline: stage K(c+1) under QK(c), V under c==0.
// ---------------------------------------------------------------------------
__global__ __launch_bounds__(256, 2) void attn_fused(
    const float* __restrict__ X,            // [16384][512] fp32
    const unsigned short* __restrict__ Kb,  // key bf16 [4096][512] natural
    const unsigned short* __restrict__ Vt,  // V^T bf16 [256][4096] natural
    float* __restrict__ Opart,              // [NS][16384][256]
    float* __restrict__ Mpart,              // [NS][16384]
    float* __restrict__ Lpart)              // [NS][16384]
{
    // LDS: sK dbuf 2x16KB (64 keys x 128 d chunk, swizzled) @0
    //      sV 32KB (256 dv x 64 keys, swizzled)             @32768
    //      stats 1KB [wm][wk][m|l][q]                       @65536
    __shared__ __align__(16) char smem[66560];
    short* sK0 = (short*)smem;
    short* sK1 = (short*)(smem + 16384);
    short* sVs = (short*)(smem + 32768);
    float* sSt = (float*)(smem + 65536);

    const int tid  = threadIdx.x;
    const int wave = tid >> 6;
    const int lane = tid & 63;
    const int l31  = lane & 31;
    const int hi   = lane >> 5;
    const int wm   = wave >> 1;
    const int wk   = wave & 1;
    const int split = blockIdx.y;
    const int q0   = blockIdx.x * 64;
    const float scale = 0.04419417382415922f;  // 1/sqrt(512)

    // Q as MFMA B-frags (swapped QK: B[k=d][col=q]), scale folded.
    // qf[t] element e = X[q0+wm*32+l31][t*16 + hi*8 + e] * scale.  128 VGPRs.
    bf16x8 qf[32];
    {
        const float* xrow = X + (size_t)(q0 + wm*32 + l31)*DDIM + hi*8;
        #pragma unroll
        for (int t = 0; t < 32; ++t) {
            float4 a = *(const float4*)(xrow + t*16);
            float4 b = *(const float4*)(xrow + t*16 + 4);
            bf16x8 q;
            q[0]=f2bf(a.x*scale); q[1]=f2bf(a.y*scale); q[2]=f2bf(a.z*scale); q[3]=f2bf(a.w*scale);
            q[4]=f2bf(b.x*scale); q[5]=f2bf(b.y*scale); q[6]=f2bf(b.z*scale); q[7]=f2bf(b.w*scale);
            qf[t] = q;
        }
    }

    // O acc: D[row=q][col=dv], 8 dv-blocks of 32.  128 VGPRs.
    f32x16 o[8];
    #pragma unroll
    for (int n = 0; n < 8; ++n)
        #pragma unroll
        for (int r = 0; r < 16; ++r) o[n][r] = 0.f;
    float m_r = -1e30f, l_r = 0.f;       // per-lane stats for q = l31

    const int jt0 = split * (NJ*64);

    // K chunk cc (128 d) of j-tile jtb_ into buf_. LDS linear (gload_lds
    // dst = uniform base + lane*16); swizzle applied on the GLOBAL src so
    // stored LDS[row][cs] = K[row][cs ^ ((row&15)<<3)] (shorts).
    #define STAGE_K(jtb_, cc_, buf_)                                          \
        do {                                                                  \
            _Pragma("unroll")                                                 \
            for (int it_ = 0; it_ < 4; ++it_) {                               \
                int row_ = wave*16 + it_*4 + (lane>>4);                       \
                const char* src_ = (const char*)Kb                            \
                    + (size_t)((jtb_) + row_)*1024 + (cc_)*256                \
                    + (((lane&15) ^ (row_&15)) << 4);                         \
                gload_lds16(src_, (char*)(buf_) + wave*4096 + it_*1024);      \
            }                                                                 \
        } while (0)

    // V^T chunk [256 dv][64 keys]; stored LDS[dv][cs] = Vt[dv][cs ^ ((dv&7)<<3)]
    #define STAGE_V(jtb_)                                                     \
        do {                                                                  \
            _Pragma("unroll")                                                 \
            for (int it_ = 0; it_ < 8; ++it_) {                               \
                int dv_ = wave*64 + it_*8 + (lane>>3);                        \
                const char* src_ = (const char*)Vt + (size_t)dv_*8192         \
                    + (size_t)(jtb_)*2 + (((lane&7) ^ (lane>>3)) << 4);       \
                gload_lds16(src_, (char*)sVs + wave*8192 + it_*1024);         \
            }                                                                 \
        } while (0)

    STAGE_K(jt0, 0, sK0);               // prologue, drained by first barrier

    const int krow = wk*32 + l31;       // A-frag key row within 64-key tile
    const int kswz = (krow & 15) << 3;  // shorts

    for (int j = 0; j < NJ; ++j) {
        const int jtb = jt0 + j*64;
        f32x16 s;                       // P^T acc: D[row=key][col=q]
        #pragma unroll
        for (int r = 0; r < 16; ++r) s[r] = 0.f;

        #pragma unroll
        for (int c = 0; c < 4; ++c) {
            __syncthreads();            // drains chunk c (+V at c==1), frees other buf
            if (c == 0) STAGE_V(jtb);   // consumed at PV, drained by c==1 barrier
            if (c < 3)            STAGE_K(jtb,    c+1, (c&1) ? sK0 : sK1);
            else if (j+1 < NJ)    STAGE_K(jtb+64, 0,   sK0);
            const short* sKc = (c&1) ? sK1 : sK0;
            const short* krb = sKc + krow*128;
            #pragma unroll
            for (int t = 0; t < 8; ++t) {
                bf16x8 kf = *(const bf16x8*)(krb + ((t*16 + hi*8) ^ kswz));
                s = __builtin_amdgcn_mfma_f32_32x32x16_bf16(kf, qf[c*8+t], s, 0, 0, 0);
            }
        }

        // ---- online softmax, fully in-lane (lane owns column q=l31; its 16
        //      regs are keys {0..3,8..11,16..19,24..27}+4hi; partner half via
        //      one shfl_xor(32)) ----
        float tmax = s[0];
        #pragma unroll
        for (int r = 1; r < 16; ++r) tmax = fmaxf(tmax, s[r]);
        tmax = fmaxf(tmax, __shfl_xor(tmax, 32));
        float mn = fmaxf(m_r, tmax);
        float alpha = __expf(m_r - mn);
        float p[16]; float tsum = 0.f;
        #pragma unroll
        for (int r = 0; r < 16; ++r) { p[r] = __expf(s[r] - mn); tsum += p[r]; }
        tsum += __shfl_xor(tsum, 32);
        l_r = l_r * alpha + tsum;
        m_r = mn;
        if (__any(alpha < 1.f)) {       // rescale O (rows are q -> alpha by row)
            #pragma unroll
            for (int r = 0; r < 16; ++r) {
                int row = (r&3) + 8*(r>>2) + 4*hi;
                float ar = __shfl(alpha, row);
                #pragma unroll
                for (int n = 0; n < 8; ++n) o[n][r] *= ar;
            }
        }

        // ---- P -> PV A-frags in-register: cvt_pk pairs + permlane32_swap.
        // frag ks needs keys ks*16 + hi*8 + {0..7}; own regs hold keys with
        // bit2==4*hi, partner lane (l^32) holds the complement. One swap
        // fills two frag words (w0,w2)/(w1,w3). ----
        bf16x8 pf[2];
        #pragma unroll
        for (int ks = 0; ks < 2; ++ks) {
            int wA, wB, wC, wD;
            asm("v_cvt_pk_bf16_f32 %0, %1, %2" : "=v"(wA) : "v"(p[8*ks+0]), "v"(p[8*ks+1]));
            asm("v_cvt_pk_bf16_f32 %0, %1, %2" : "=v"(wB) : "v"(p[8*ks+2]), "v"(p[8*ks+3]));
            asm("v_cvt_pk_bf16_f32 %0, %1, %2" : "=v"(wC) : "v"(p[8*ks+4]), "v"(p[8*ks+5]));
            asm("v_cvt_pk_bf16_f32 %0, %1, %2" : "=v"(wD) : "v"(p[8*ks+6]), "v"(p[8*ks+7]));
            asm("v_permlane32_swap_b32 %0, %1" : "+v"(wA), "+v"(wC));
            asm("v_permlane32_swap_b32 %0, %1" : "+v"(wB), "+v"(wD));
            union { int w[4]; bf16x8 v; } u;
            u.w[0] = wA; u.w[1] = wB; u.w[2] = wC; u.w[3] = wD;
            pf[ks] = u.v;
        }

        // ---- PV: O += P * V^T (V drained long ago; wave's own 32 keys) ----
        #pragma unroll
        for (int ks = 0; ks < 2; ++ks)
            #pragma unroll
            for (int n = 0; n < 8; ++n) {
                int dv = n*32 + l31;
                bf16x8 vf = *(const bf16x8*)(sVs + dv*64
                                + ((wk*32 + ks*16 + hi*8) ^ ((dv&7)<<3)));
                o[n] = __builtin_amdgcn_mfma_f32_32x32x16_bf16(pf[ks], vf, o[n], 0, 0, 0);
            }
    }
    #undef STAGE_K
    #undef STAGE_V

    // ---- epilogue: merge the two wk key-half partials per wm (exact
    // split-combine math), then write unnormalized O + (M,L) per row ----
    __syncthreads();
    if (lane < 32) {
        sSt[((wm*2+wk)*2+0)*32 + lane] = m_r;
        sSt[((wm*2+wk)*2+1)*32 + lane] = l_r;
    }
    __syncthreads();
    float* obuf = (float*)(smem + wm*32768);    // 32 KB scratch per wm pair
    if (wk == 1) {
        #pragma unroll
        for (int n = 0; n < 8; ++n)
            #pragma unroll
            for (int r = 0; r < 16; ++r) {
                int row = (r&3) + 8*(r>>2) + 4*hi;
                obuf[row*256 + n*32 + l31] = o[n][r];
            }
    }
    __syncthreads();
    if (wk == 0) {
        float m0 = sSt[((wm*2+0)*2+0)*32 + l31];
        float m1 = sSt[((wm*2+1)*2+0)*32 + l31];
        float l0 = sSt[((wm*2+0)*2+1)*32 + l31];
        float l1 = sSt[((wm*2+1)*2+1)*32 + l31];
        float M  = fmaxf(m0, m1);
        float w0 = __expf(m0 - M), w1 = __expf(m1 - M);
        const size_t base = (size_t)split * NROWS;
        const int gr0 = q0 + wm*32;
        if (lane < 32) {
            Mpart[base + gr0 + lane] = M;
            Lpart[base + gr0 + lane] = l0*w0 + l1*w1;
        }
        #pragma unroll
        for (int r = 0; r < 16; ++r) {
            int row = (r&3) + 8*(r>>2) + 4*hi;
            float w0r = __shfl(w0, row);
            float w1r = __shfl(w1, row);
            float* orow = Opart + (base + gr0 + row) * (size_t)DVDIM;
            #pragma unroll
            for (int n = 0; n < 8; ++n)
                orow[n*32 + l31] = o[n][r]*w0r + obuf[row*256 + n*32 + l31]*w1r;
        }
    }
}

// ---------------------------------------------------------------------------
// Combine NS split partials: out = sum_s(Os*ws) / sum_s(ls*ws), ws=exp(ms-M).
// grid = NROWS/4, block = 256: 4 rows/block, one float4 per thread. Coalesced.
// ---------------------------------------------------------------------------
__global__ void combine_splits(
    const float* __restrict__ Opart, const float* __restrict__ Mpart,
    const float* __restrict__ Lpart, float* __restrict__ out)
{
    const int row = blockIdx.x * 4 + (threadIdx.x >> 6);
    const int dv4 = (threadIdx.x & 63) * 4;
    float M = -1e30f;
    #pragma unroll
    for (int s = 0; s < NS; ++s) M = fmaxf(M, Mpart[(size_t)s*NROWS + row]);
    float denom = 0.f;
    float4 acc = make_float4(0.f, 0.f, 0.f, 0.f);
    #pragma unroll
    for (int s = 0; s < NS; ++s) {
        float w = __expf(Mpart[(size_t)s*NROWS + row] - M);
        denom += Lpart[(size_t)s*NROWS + row] * w;
        float4 ov = *(const float4*)(Opart + ((size_t)s*NROWS + row)*DVDIM + dv4);
        acc.x += ov.x*w; acc.y += ov.y*w; acc.z += ov.z*w; acc.w += ov.w*w;
    }
    float inv = 1.0f / denom;
    *(float4*)(out + (size_t)row*DVDIM + dv4)
        = make_float4(acc.x*inv, acc.y*inv, acc.z*inv, acc.w*inv);
}

extern "C" void kernel_launch(void* const* d_in, const int* in_sizes, int n_in,
                              void* d_out, int out_size, void* d_ws, size_t ws_size,
                              hipStream_t stream) {
    const float* X  = (const float*)d_in[0];   // [8,2048,512]
    const float* Y  = (const float*)d_in[1];   // [4096,512]
    const float* Z  = (const float*)d_in[2];   // [4096,512]
    const float* Wk = (const float*)d_in[3];   // [512,512]
    const float* Wv = (const float*)d_in[4];   // [256,512]
    float* out = (float*)d_out;

    // workspace layout (~38.3 MB)
    char* ws = (char*)d_ws;
    unsigned short* keyb = (unsigned short*)ws;                    // 4 MB, natural [4096][512]
    unsigned short* vtb  = (unsigned short*)(ws + (4u<<20));       // 2 MB, natural [256][4096]
    float* Opart = (float*)(ws + (6u<<20));                        // NS x 16 MB
    float* Mpart = (float*)(ws + (6u<<20) + (size_t)NS*NROWS*DVDIM*4);
    float* Lpart = Mpart + (size_t)NS*NROWS;

    // both projections, one launch
    proj_gemms<<<dim3(64, 8, 2), dim3(256), 0, stream>>>(Y, Z, Wk, Wv, keyb, vtb);
    // fused attention over NS SK-splits
    attn_fused<<<dim3(NROWS/64, NS), dim3(256), 0, stream>>>(
        X, keyb, vtb, Opart, Mpart, Lpart);
    // merge splits
    combine_splits<<<dim3(NROWS/4), dim3(256), 0, stream>>>(Opart, Mpart, Lpart, out);
}

// Round 2
// 334.878 us; speedup vs baseline: 1.1928x; 1.1928x over previous
//
#include <hip/hip_runtime.h>
#include <hip/hip_bf16.h>

// Problem constants
#define NB    8
#define SQN   2048
#define SKN   4096
#define DDIM  512
#define DVDIM 256
#define NROWS (NB*SQN)      // 16384
#define NS    2             // SK splits
#define NJ    ((SKN/64)/NS) // 32 j-iterations per split (64 keys each)

typedef __attribute__((ext_vector_type(8)))  short bf16x8;   // 8 bf16 = 4 VGPRs (MFMA A/B frag)
typedef __attribute__((ext_vector_type(4)))  short bf16x4;
typedef __attribute__((ext_vector_type(4)))  float f32x4;    // 16x16 MFMA C/D frag
typedef __attribute__((ext_vector_type(16))) float f32x16;   // 32x32 MFMA C/D frag

// fp32 -> bf16 round-to-nearest-even, bit pattern as short
__device__ __forceinline__ short f2bf(float f) {
    unsigned u = __float_as_uint(f);
    return (short)((u + 0x7FFFu + ((u >> 16) & 1u)) >> 16);
}

// async global->LDS, 16B per lane; LDS dst = wave-uniform base + lane*16,
// global src is per-lane (used to pre-arrange frag-linear LDS layouts)
__device__ __forceinline__ void gload_lds16(const void* g, void* l) {
    __builtin_amdgcn_global_load_lds(
        (const __attribute__((address_space(1))) unsigned int*)g,
        (__attribute__((address_space(3))) unsigned int*)l, 16, 0, 0);
}

// ---------------------------------------------------------------------------
// Fused projection GEMMs, one launch. grid = (64, 8, 2).  (unchanged)
//  z=0: key[s][d]  = sum_c Y[s][c]*Wk[d][c]   M=4096 N=512
//  z=1: vt[dv][s]  = sum_c Wv[dv][c]*Z[s][c]  M=256  N=4096 (uses 256 of 512 tiles)
// ---------------------------------------------------------------------------
__global__ __launch_bounds__(256, 2) void proj_gemms(
    const float* __restrict__ Y, const float* __restrict__ Z,
    const float* __restrict__ Wk, const float* __restrict__ Wv,
    unsigned short* __restrict__ keyb, unsigned short* __restrict__ vtb)
{
    __shared__ short sA[64*128];   // 16 KB
    __shared__ short sB[64*128];   // 16 KB
    const float *A, *Bm;
    unsigned short* C;
    int N, m0, n0;
    if (blockIdx.z == 0) {
        A = Y; Bm = Wk; C = keyb; N = DDIM;
        m0 = blockIdx.x * 64; n0 = blockIdx.y * 64;
    } else {
        int lin = blockIdx.x * 8 + blockIdx.y;
        if (lin >= 256) return;                 // value GEMM needs 256 tiles
        A = Wv; Bm = Z; C = vtb; N = SKN;
        m0 = (lin >> 6) * 64; n0 = (lin & 63) * 64;
    }
    const int tid  = threadIdx.x;
    const int wave = tid >> 6;
    const int lane = tid & 63;
    const int quad = lane >> 4;
    const int l15  = lane & 15;

    f32x4 acc[4];
    #pragma unroll
    for (int n = 0; n < 4; ++n) { acc[n][0]=0.f; acc[n][1]=0.f; acc[n][2]=0.f; acc[n][3]=0.f; }

    float4 ra[8], rb[8];
    #pragma unroll
    for (int it = 0; it < 8; ++it) {            // prefetch kc=0
        int f = it*1024 + tid*4, row = f >> 7, col = f & 127;
        ra[it] = *(const float4*)(A  + (size_t)(m0+row)*DDIM + col);
        rb[it] = *(const float4*)(Bm + (size_t)(n0+row)*DDIM + col);
    }

    for (int kc = 0; kc < DDIM; kc += 128) {
        __syncthreads();                        // LDS free (prev MFMA done)
        #pragma unroll
        for (int it = 0; it < 8; ++it) {
            int f = it*1024 + tid*4;
            bf16x4 a4; a4[0]=f2bf(ra[it].x); a4[1]=f2bf(ra[it].y); a4[2]=f2bf(ra[it].z); a4[3]=f2bf(ra[it].w);
            *(bf16x4*)(sA + f) = a4;
            bf16x4 b4; b4[0]=f2bf(rb[it].x); b4[1]=f2bf(rb[it].y); b4[2]=f2bf(rb[it].z); b4[3]=f2bf(rb[it].w);
            *(bf16x4*)(sB + f) = b4;
        }
        __syncthreads();                        // staged visible
        if (kc + 128 < DDIM) {                  // prefetch kc+1 (in flight under MFMA)
            #pragma unroll
            for (int it = 0; it < 8; ++it) {
                int f = it*1024 + tid*4, row = f >> 7, col = f & 127;
                ra[it] = *(const float4*)(A  + (size_t)(m0+row)*DDIM + kc + 128 + col);
                rb[it] = *(const float4*)(Bm + (size_t)(n0+row)*DDIM + kc + 128 + col);
            }
        }
        #pragma unroll
        for (int t = 0; t < 4; ++t) {
            bf16x8 af = *(const bf16x8*)(sA + (wave*16 + l15)*128 + t*32 + quad*8);
            #pragma unroll
            for (int n = 0; n < 4; ++n) {
                bf16x8 bfr = *(const bf16x8*)(sB + (n*16 + l15)*128 + t*32 + quad*8);
                acc[n] = __builtin_amdgcn_mfma_f32_16x16x32_bf16(af, bfr, acc[n], 0, 0, 0);
            }
        }
    }
    #pragma unroll
    for (int n = 0; n < 4; ++n)
        #pragma unroll
        for (int r = 0; r < 4; ++r) {
            int m  = m0 + wave*16 + quad*4 + r;
            int nn = n0 + n*16 + l15;
            C[(size_t)m*N + nn] = (unsigned short)f2bf(acc[n][r]);
        }
}

// ---------------------------------------------------------------------------
// Fused attention, 32x32 swapped-operand, R2 fixes:
//  - wk pair splits PV dv-range (o[4]=64 VGPR, not o[8]=128) -> no spill.
//    Requires shared softmax max across wk: 2 small stat-exchange barriers/j.
//    Epilogue O-merge eliminated (disjoint dv, shared m/l).
//  - K/V staged FRAG-LINEAR in LDS (tile = [frag][lane]x16B) via per-lane
//    global src + linear gload_lds dst: every hot-loop LDS read is
//    uniform_base + lane*16 + imm  -> zero bank conflicts, zero addr VALU.
//  - P exchanged between wk partners lane-linear (8 KB), pf built in-reg
//    via cvt_pk + permlane32_swap (proven correct in R1).
// grid = (NROWS/64, NS), block = 256 = 4 waves (wm = wave>>1 Q-rows 32..,
// wk = wave&1 key-half for QK / dv-half for PV).
// ---------------------------------------------------------------------------
__global__ __launch_bounds__(256, 2) void attn_fused(
    const float* __restrict__ X,            // [16384][512] fp32
    const unsigned short* __restrict__ Kb,  // key bf16 [4096][512] natural
    const unsigned short* __restrict__ Vt,  // V^T bf16 [256][4096] natural
    float* __restrict__ Opart,              // [NS][16384][256]
    float* __restrict__ Mpart,              // [NS][16384]
    float* __restrict__ Lpart)              // [NS][16384]
{
    // 0      : sK dbuf 2 x 16KB, frag-linear: tile T=(t*2+kh), T*1024+lane*16
    //          holds K[kh*32 + l31][c*128 + t*16 + hi*8 + 0..7]
    // 32768  : sV 32KB, frag-linear: tile T=(nn*4+g), holds
    //          Vt[nn*32 + l31][g*16 + hi*8 + 0..7] for the current j-tile
    // 65536  : sPex 8KB: [wm=2][g=4][lane]x16B P A-frags
    // 73728  : sSt 1KB:  [wm][wk][slot: 0=tmax 1=tsum][32 q] floats
    __shared__ __align__(16) char smem[74752];
    char* sK0  = smem;
    char* sK1  = smem + 16384;
    char* sV   = smem + 32768;
    char* sPex = smem + 65536;
    float* sSt = (float*)(smem + 73728);

    const int tid  = threadIdx.x;
    const int wave = tid >> 6;
    const int lane = tid & 63;
    const int l31  = lane & 31;
    const int hi   = lane >> 5;
    const int wm   = wave >> 1;
    const int wk   = wave & 1;
    const int split = blockIdx.y;
    const int q0   = blockIdx.x * 64;
    const float scale = 0.04419417382415922f;  // 1/sqrt(512)

    // Q as MFMA B-frags (swapped QK: B[k=d][col=q]), scale folded.
    // qf[c*8+t] elem e = X[q0+wm*32+l31][c*128 + t*16 + hi*8 + e]*scale. 128 VGPR.
    bf16x8 qf[32];
    {
        const float* xrow = X + (size_t)(q0 + wm*32 + l31)*DDIM + hi*8;
        #pragma unroll
        for (int t = 0; t < 32; ++t) {
            float4 a = *(const float4*)(xrow + t*16);
            float4 b = *(const float4*)(xrow + t*16 + 4);
            bf16x8 q;
            q[0]=f2bf(a.x*scale); q[1]=f2bf(a.y*scale); q[2]=f2bf(a.z*scale); q[3]=f2bf(a.w*scale);
            q[4]=f2bf(b.x*scale); q[5]=f2bf(b.y*scale); q[6]=f2bf(b.z*scale); q[7]=f2bf(b.w*scale);
            qf[t] = q;
        }
    }

    // O acc: D[row=q][col=dv], wave's dv-half = wk*128 + n*32 + l31. 64 VGPR.
    f32x16 o[4];
    #pragma unroll
    for (int n = 0; n < 4; ++n)
        #pragma unroll
        for (int r = 0; r < 16; ++r) o[n][r] = 0.f;
    float m_r = -1e30f, l_r = 0.f;       // shared across wk pair (joint max)

    const int jt0 = split * (NJ*64);

    // stage K chunk cc (128 d) of j-tile jtb_ frag-linear into bufbase_.
    // 16 tiles of 1KB; wave stages tiles wave*4..+3. T=(t<<1)|kh.
    #define STAGE_K(jtb_, cc_, bufbase_)                                      \
        do {                                                                  \
            _Pragma("unroll")                                                 \
            for (int it_ = 0; it_ < 4; ++it_) {                               \
                int T_ = wave*4 + it_;                                        \
                const char* src_ = (const char*)Kb                            \
                    + (size_t)((jtb_) + (T_&1)*32 + l31)*1024                 \
                    + (cc_)*256 + (T_>>1)*32 + hi*16;                         \
                gload_lds16(src_, (bufbase_) + T_*1024);                      \
            }                                                                 \
        } while (0)

    // stage V^T j-tile frag-linear: 32 tiles of 1KB; wave stages wave*8..+7.
    // T=(nn<<2)|g holds Vt[nn*32+l31][jtb + g*16 + hi*8 + 0..7].
    #define STAGE_V(jtb_)                                                     \
        do {                                                                  \
            _Pragma("unroll")                                                 \
            for (int it_ = 0; it_ < 8; ++it_) {                               \
                int T_ = wave*8 + it_;                                        \
                const char* src_ = (const char*)Vt                            \
                    + (size_t)((T_>>2)*32 + l31)*8192                         \
                    + (size_t)((jtb_) + (T_&3)*16 + hi*8)*2;                  \
                gload_lds16(src_, sV + T_*1024);                              \
            }                                                                 \
        } while (0)

    STAGE_K(jt0, 0, sK0);               // prologue, drained by first barrier

    for (int j = 0; j < NJ; ++j) {
        const int jtb = jt0 + j*64;
        f32x16 s;                       // P^T acc: D[row=key][col=q]
        #pragma unroll
        for (int r = 0; r < 16; ++r) s[r] = 0.f;

        #pragma unroll
        for (int c = 0; c < 4; ++c) {
            __syncthreads();            // drains chunk c (+V at c==1), frees other buf
            if (c == 0) STAGE_V(jtb);   // consumed at PV, drained by c==1 barrier
            if (c < 3) STAGE_K(jtb, c+1, (c&1) ? sK0 : sK1);
            const char* kb = ((c&1) ? sK1 : sK0) + wk*1024 + lane*16;
            #pragma unroll
            for (int t = 0; t < 8; ++t) {
                bf16x8 kf = *(const bf16x8*)(kb + t*2048);
                s = __builtin_amdgcn_mfma_f32_32x32x16_bf16(kf, qf[c*8+t], s, 0, 0, 0);
            }
        }

        // ---- softmax: in-lane (lane owns q=l31; 16 keys + hi-partner via
        //      shfl_xor(32)), then joint max across wk pair via LDS ----
        float tmax = fmaxf(fmaxf(fmaxf(s[0],s[1]),fmaxf(s[2],s[3])),
                           fmaxf(fmaxf(s[4],s[5]),fmaxf(s[6],s[7])));
        tmax = fmaxf(tmax, fmaxf(fmaxf(fmaxf(s[8],s[9]),fmaxf(s[10],s[11])),
                                 fmaxf(fmaxf(s[12],s[13]),fmaxf(s[14],s[15]))));
        tmax = fmaxf(tmax, __shfl_xor(tmax, 32));
        if (lane < 32) sSt[((wm*2+wk)*2+0)*32 + lane] = tmax;
        __syncthreads();                                        // barrier 5
        float tmax_o = sSt[((wm*2+(wk^1))*2+0)*32 + l31];
        const float mn = fmaxf(m_r, fmaxf(tmax, tmax_o));
        const float alpha = __expf(m_r - mn);
        float tsum = 0.f;
        #pragma unroll
        for (int r = 0; r < 16; ++r) { float pv = __expf(s[r] - mn); s[r] = pv; tsum += pv; }
        tsum += __shfl_xor(tsum, 32);

        // P -> PV A-frags in-register (proven in R1): own 32 keys = global
        // key-slices g = 2*wk + {0,1}
        bf16x8 pf[2];
        #pragma unroll
        for (int ks = 0; ks < 2; ++ks) {
            int wA, wB, wC, wD;
            asm("v_cvt_pk_bf16_f32 %0, %1, %2" : "=v"(wA) : "v"(s[8*ks+0]), "v"(s[8*ks+1]));
            asm("v_cvt_pk_bf16_f32 %0, %1, %2" : "=v"(wB) : "v"(s[8*ks+2]), "v"(s[8*ks+3]));
            asm("v_cvt_pk_bf16_f32 %0, %1, %2" : "=v"(wC) : "v"(s[8*ks+4]), "v"(s[8*ks+5]));
            asm("v_cvt_pk_bf16_f32 %0, %1, %2" : "=v"(wD) : "v"(s[8*ks+6]), "v"(s[8*ks+7]));
            asm("v_permlane32_swap_b32 %0, %1" : "+v"(wA), "+v"(wC));
            asm("v_permlane32_swap_b32 %0, %1" : "+v"(wB), "+v"(wD));
            union { int w[4]; bf16x8 v; } u;
            u.w[0] = wA; u.w[1] = wB; u.w[2] = wC; u.w[3] = wD;
            pf[ks] = u.v;
        }
        *(bf16x8*)(sPex + (wm*4 + wk*2 + 0)*1024 + lane*16) = pf[0];
        *(bf16x8*)(sPex + (wm*4 + wk*2 + 1)*1024 + lane*16) = pf[1];
        if (lane < 32) sSt[((wm*2+wk)*2+1)*32 + lane] = tsum;
        __syncthreads();                                        // barrier 6
        float tsum_o = sSt[((wm*2+(wk^1))*2+1)*32 + l31];
        l_r = l_r*alpha + (tsum + tsum_o);
        m_r = mn;
        if (__any(alpha < 1.f)) {       // rescale O (alpha indexed by q-row)
            #pragma unroll
            for (int r = 0; r < 16; ++r) {
                int row = (r&3) + 8*(r>>2) + 4*hi;
                float ar = __shfl(alpha, row);
                #pragma unroll
                for (int n = 0; n < 4; ++n) o[n][r] *= ar;
            }
        }

        // prefetch next j-tile chunk 0 (sK0 free since c==3 barrier);
        // overlaps PV, drained by next j's c==0 barrier
        if (j + 1 < NJ) STAGE_K(jtb + 64, 0, sK0);

        // ---- PV: O[dv-half wk] += P(all 64 keys) * V^T; all reads lane-linear ----
        const char* vb = sV + wk*16384 + lane*16;
        const char* pb = sPex + wm*4096 + lane*16;
        #pragma unroll
        for (int g = 0; g < 4; ++g) {
            bf16x8 pa = ((g >> 1) == wk) ? pf[g & 1]
                        : *(const bf16x8*)(pb + g*1024);
            #pragma unroll
            for (int n = 0; n < 4; ++n) {
                bf16x8 vf = *(const bf16x8*)(vb + (n*4 + g)*1024);
                o[n] = __builtin_amdgcn_mfma_f32_32x32x16_bf16(pa, vf, o[n], 0, 0, 0);
            }
        }
    }
    #undef STAGE_K
    #undef STAGE_V

    // ---- epilogue: shared (m,l) across wk; disjoint dv halves -> no merge ----
    const size_t base = (size_t)split * NROWS;
    const int gr0 = q0 + wm*32;
    if (wk == 0 && lane < 32) {
        Mpart[base + gr0 + lane] = m_r;
        Lpart[base + gr0 + lane] = l_r;
    }
    #pragma unroll
    for (int r = 0; r < 16; ++r) {
        int row = (r&3) + 8*(r>>2) + 4*hi;
        float* orow = Opart + (base + gr0 + row) * (size_t)DVDIM + wk*128;
        #pragma unroll
        for (int n = 0; n < 4; ++n)
            orow[n*32 + l31] = o[n][r];
    }
}

// ---------------------------------------------------------------------------
// Combine NS split partials: out = sum_s(Os*ws) / sum_s(ls*ws), ws=exp(ms-M).
// grid = NROWS/4, block = 256: 4 rows/block, one float4 per thread. Coalesced.
// ---------------------------------------------------------------------------
__global__ void combine_splits(
    const float* __restrict__ Opart, const float* __restrict__ Mpart,
    const float* __restrict__ Lpart, float* __restrict__ out)
{
    const int row = blockIdx.x * 4 + (threadIdx.x >> 6);
    const int dv4 = (threadIdx.x & 63) * 4;
    float M = -1e30f;
    #pragma unroll
    for (int s = 0; s < NS; ++s) M = fmaxf(M, Mpart[(size_t)s*NROWS + row]);
    float denom = 0.f;
    float4 acc = make_float4(0.f, 0.f, 0.f, 0.f);
    #pragma unroll
    for (int s = 0; s < NS; ++s) {
        float w = __expf(Mpart[(size_t)s*NROWS + row] - M);
        denom += Lpart[(size_t)s*NROWS + row] * w;
        float4 ov = *(const float4*)(Opart + ((size_t)s*NROWS + row)*DVDIM + dv4);
        acc.x += ov.x*w; acc.y += ov.y*w; acc.z += ov.z*w; acc.w += ov.w*w;
    }
    float inv = 1.0f / denom;
    *(float4*)(out + (size_t)row*DVDIM + dv4)
        = make_float4(acc.x*inv, acc.y*inv, acc.z*inv, acc.w*inv);
}

extern "C" void kernel_launch(void* const* d_in, const int* in_sizes, int n_in,
                              void* d_out, int out_size, void* d_ws, size_t ws_size,
                              hipStream_t stream) {
    const float* X  = (const float*)d_in[0];   // [8,2048,512]
    const float* Y  = (const float*)d_in[1];   // [4096,512]
    const float* Z  = (const float*)d_in[2];   // [4096,512]
    const float* Wk = (const float*)d_in[3];   // [512,512]
    const float* Wv = (const float*)d_in[4];   // [256,512]
    float* out = (float*)d_out;

    // workspace layout (~38.3 MB)
    char* ws = (char*)d_ws;
    unsigned short* keyb = (unsigned short*)ws;                    // 4 MB, natural [4096][512]
    unsigned short* vtb  = (unsigned short*)(ws + (4u<<20));       // 2 MB, natural [256][4096]
    float* Opart = (float*)(ws + (6u<<20));                        // NS x 16 MB
    float* Mpart = (float*)(ws + (6u<<20) + (size_t)NS*NROWS*DVDIM*4);
    float* Lpart = Mpart + (size_t)NS*NROWS;

    // both projections, one launch
    proj_gemms<<<dim3(64, 8, 2), dim3(256), 0, stream>>>(Y, Z, Wk, Wv, keyb, vtb);
    // fused attention over NS SK-splits
    attn_fused<<<dim3(NROWS/64, NS), dim3(256), 0, stream>>>(
        X, keyb, vtb, Opart, Mpart, Lpart);
    // merge splits
    combine_splits<<<dim3(NROWS/4), dim3(256), 0, stream>>>(Opart, Mpart, Lpart, out);
}

// Round 3
// 266.813 us; speedup vs baseline: 1.4971x; 1.2551x over previous
//
#include <hip/hip_runtime.h>
#include <hip/hip_bf16.h>

// Problem constants
#define NB    8
#define SQN   2048
#define SKN   4096
#define DDIM  512
#define DVDIM 256
#define NROWS (NB*SQN)      // 16384
#define NS    2             // SK splits
#define NJ    ((SKN/64)/NS) // 32 j-iterations per split (64 keys each)

typedef __attribute__((ext_vector_type(8)))  short bf16x8;   // 8 bf16 = 4 VGPRs (MFMA A/B frag)
typedef __attribute__((ext_vector_type(4)))  short bf16x4;
typedef __attribute__((ext_vector_type(4)))  float f32x4;    // 16x16 MFMA C/D frag
typedef __attribute__((ext_vector_type(16))) float f32x16;   // 32x32 MFMA C/D frag

// fp32 -> bf16 round-to-nearest-even, bit pattern as short
__device__ __forceinline__ short f2bf(float f) {
    unsigned u = __float_as_uint(f);
    return (short)((u + 0x7FFFu + ((u >> 16) & 1u)) >> 16);
}

// async global->LDS, 16B per lane; LDS dst = wave-uniform base + lane*16,
// global src is per-lane (used to pre-arrange frag-linear LDS layouts)
__device__ __forceinline__ void gload_lds16(const void* g, void* l) {
    __builtin_amdgcn_global_load_lds(
        (const __attribute__((address_space(1))) unsigned int*)g,
        (__attribute__((address_space(3))) unsigned int*)l, 16, 0, 0);
}

// counted-vmcnt barrier: waits only the oldest loads (keeps N newest in
// flight across the barrier) — the T3/T4 discipline. sched_barrier fences
// per rule #18 (compiler must not hoist MFMA/ds ops across the asm wait).
#define BAR_VM(N_) do {                                                       \
    asm volatile("s_waitcnt vmcnt(" #N_ ")" ::: "memory");                    \
    __builtin_amdgcn_sched_barrier(0);                                        \
    __builtin_amdgcn_s_barrier();                                             \
    __builtin_amdgcn_sched_barrier(0);                                        \
} while (0)

// LDS-only barrier (P/stat exchange): vm prefetches stay in flight.
#define BAR_LGKM() do {                                                       \
    asm volatile("s_waitcnt lgkmcnt(0)" ::: "memory");                        \
    __builtin_amdgcn_sched_barrier(0);                                        \
    __builtin_amdgcn_s_barrier();                                             \
    __builtin_amdgcn_sched_barrier(0);                                        \
} while (0)

// ---------------------------------------------------------------------------
// Fused projection GEMMs, one launch. grid = (64, 8, 2).  (unchanged)
//  z=0: key[s][d]  = sum_c Y[s][c]*Wk[d][c]   M=4096 N=512
//  z=1: vt[dv][s]  = sum_c Wv[dv][c]*Z[s][c]  M=256  N=4096 (uses 256 of 512 tiles)
// ---------------------------------------------------------------------------
__global__ __launch_bounds__(256, 2) void proj_gemms(
    const float* __restrict__ Y, const float* __restrict__ Z,
    const float* __restrict__ Wk, const float* __restrict__ Wv,
    unsigned short* __restrict__ keyb, unsigned short* __restrict__ vtb)
{
    __shared__ short sA[64*128];   // 16 KB
    __shared__ short sB[64*128];   // 16 KB
    const float *A, *Bm;
    unsigned short* C;
    int N, m0, n0;
    if (blockIdx.z == 0) {
        A = Y; Bm = Wk; C = keyb; N = DDIM;
        m0 = blockIdx.x * 64; n0 = blockIdx.y * 64;
    } else {
        int lin = blockIdx.x * 8 + blockIdx.y;
        if (lin >= 256) return;                 // value GEMM needs 256 tiles
        A = Wv; Bm = Z; C = vtb; N = SKN;
        m0 = (lin >> 6) * 64; n0 = (lin & 63) * 64;
    }
    const int tid  = threadIdx.x;
    const int wave = tid >> 6;
    const int lane = tid & 63;
    const int quad = lane >> 4;
    const int l15  = lane & 15;

    f32x4 acc[4];
    #pragma unroll
    for (int n = 0; n < 4; ++n) { acc[n][0]=0.f; acc[n][1]=0.f; acc[n][2]=0.f; acc[n][3]=0.f; }

    float4 ra[8], rb[8];
    #pragma unroll
    for (int it = 0; it < 8; ++it) {            // prefetch kc=0
        int f = it*1024 + tid*4, row = f >> 7, col = f & 127;
        ra[it] = *(const float4*)(A  + (size_t)(m0+row)*DDIM + col);
        rb[it] = *(const float4*)(Bm + (size_t)(n0+row)*DDIM + col);
    }

    for (int kc = 0; kc < DDIM; kc += 128) {
        __syncthreads();                        // LDS free (prev MFMA done)
        #pragma unroll
        for (int it = 0; it < 8; ++it) {
            int f = it*1024 + tid*4;
            bf16x4 a4; a4[0]=f2bf(ra[it].x); a4[1]=f2bf(ra[it].y); a4[2]=f2bf(ra[it].z); a4[3]=f2bf(ra[it].w);
            *(bf16x4*)(sA + f) = a4;
            bf16x4 b4; b4[0]=f2bf(rb[it].x); b4[1]=f2bf(rb[it].y); b4[2]=f2bf(rb[it].z); b4[3]=f2bf(rb[it].w);
            *(bf16x4*)(sB + f) = b4;
        }
        __syncthreads();                        // staged visible
        if (kc + 128 < DDIM) {                  // prefetch kc+1 (in flight under MFMA)
            #pragma unroll
            for (int it = 0; it < 8; ++it) {
                int f = it*1024 + tid*4, row = f >> 7, col = f & 127;
                ra[it] = *(const float4*)(A  + (size_t)(m0+row)*DDIM + kc + 128 + col);
                rb[it] = *(const float4*)(Bm + (size_t)(n0+row)*DDIM + kc + 128 + col);
            }
        }
        #pragma unroll
        for (int t = 0; t < 4; ++t) {
            bf16x8 af = *(const bf16x8*)(sA + (wave*16 + l15)*128 + t*32 + quad*8);
            #pragma unroll
            for (int n = 0; n < 4; ++n) {
                bf16x8 bfr = *(const bf16x8*)(sB + (n*16 + l15)*128 + t*32 + quad*8);
                acc[n] = __builtin_amdgcn_mfma_f32_16x16x32_bf16(af, bfr, acc[n], 0, 0, 0);
            }
        }
    }
    #pragma unroll
    for (int n = 0; n < 4; ++n)
        #pragma unroll
        for (int r = 0; r < 4; ++r) {
            int m  = m0 + wave*16 + quad*4 + r;
            int nn = n0 + n*16 + l15;
            C[(size_t)m*N + nn] = (unsigned short)f2bf(acc[n][r]);
        }
}

// ---------------------------------------------------------------------------
// Fused attention, R3: 128 Q-rows/block (8 waves: wm=0..3 x wk=0..1),
// grid = 256 blocks = 1/CU; XCD-split swizzle (XCD 0-3 <- split 0,
// XCD 4-7 <- split 1) so each XCD's L2 holds only ONE split's K+V (3 MB
// < 4 MB) -> K/V L2-resident; K tri-buffer with 2-phase-deep prefetch and
// counted-vmcnt barriers (in-flight loads never drained by barriers).
// Per-wave math (QK frag-linear reads, in-lane softmax, P-exchange,
// dv-split PV) identical to R2 (verified, absmax 9.8e-4).
//
// Pipeline, phase g = j*4+c (K chunk g lives in phys buf g%3):
//   phase g: BAR(vmcnt keep) -> issue K(g+2) [+V(j) at c0] -> QK(c)
//   keeps: c0:2  c1:6  c2:6  c3:2 (last j: 0).  2 lgkm-only bars in softmax.
// ---------------------------------------------------------------------------
__global__ __launch_bounds__(512, 2) void attn_fused(
    const float* __restrict__ X,            // [16384][512] fp32
    const unsigned short* __restrict__ Kb,  // key bf16 [4096][512] natural
    const unsigned short* __restrict__ Vt,  // V^T bf16 [256][4096] natural
    float* __restrict__ Opart,              // [NS][16384][256]
    float* __restrict__ Mpart,              // [NS][16384]
    float* __restrict__ Lpart)              // [NS][16384]
{
    // 0     : K phys bufs 3 x 16KB, frag-linear (tile (kh? it)*: see STAGE_K)
    // 49152 : sV 32KB frag-linear
    // 81920 : sPex 16KB [wm=4][g=4][lane]x16B
    // 98304 : sSt 2KB [wave=8][slot=2][32] floats
    __shared__ __align__(16) char smem[100352];
    char* sV   = smem + 49152;
    char* sPex = smem + 81920;
    float* sSt = (float*)(smem + 98304);

    const int tid  = threadIdx.x;
    const int wave = tid >> 6;
    const int lane = tid & 63;
    const int l31  = lane & 31;
    const int hi   = lane >> 5;
    const int wm   = wave >> 1;
    const int wk   = wave & 1;

    // XCD-split swizzle: dispatch round-robins linear id over 8 XCDs.
    const int bid   = blockIdx.x;          // 0..255
    const int xcd   = bid & 7;
    const int slot  = bid >> 3;            // 0..31
    const int split = xcd >> 2;            // XCD 0-3 -> split 0, 4-7 -> split 1
    const int q0    = ((xcd & 3)*32 + slot) * 128;
    const float scale = 0.04419417382415922f;  // 1/sqrt(512)

    // Q as MFMA B-frags (swapped QK: B[k=d][col=q]), scale folded. 128 VGPR.
    bf16x8 qf[32];
    {
        const float* xrow = X + (size_t)(q0 + wm*32 + l31)*DDIM + hi*8;
        #pragma unroll
        for (int t = 0; t < 32; ++t) {
            float4 a = *(const float4*)(xrow + t*16);
            float4 b = *(const float4*)(xrow + t*16 + 4);
            bf16x8 q;
            q[0]=f2bf(a.x*scale); q[1]=f2bf(a.y*scale); q[2]=f2bf(a.z*scale); q[3]=f2bf(a.w*scale);
            q[4]=f2bf(b.x*scale); q[5]=f2bf(b.y*scale); q[6]=f2bf(b.z*scale); q[7]=f2bf(b.w*scale);
            qf[t] = q;
        }
    }

    // O acc: D[row=q][col=dv], wave's dv-half = wk*128 + n*32 + l31. 64 VGPR.
    f32x16 o[4];
    #pragma unroll
    for (int n = 0; n < 4; ++n)
        #pragma unroll
        for (int r = 0; r < 16; ++r) o[n][r] = 0.f;
    float m_r = -1e30f, l_r = 0.f;       // shared across wk pair (joint max)

    const int jt0 = split * (NJ*64);

    // stage K chunk cc (128 d) of 64-key tile jtb_ frag-linear into bufp_.
    // 16 tiles of 1KB; 8 waves stage 2 each: tile (wave*2+it): kh=it, trow=wave.
    #define STAGE_K(jtb_, cc_, bufp_)                                         \
        do {                                                                  \
            _Pragma("unroll")                                                 \
            for (int it_ = 0; it_ < 2; ++it_) {                               \
                const char* src_ = (const char*)Kb                            \
                    + (size_t)((jtb_) + it_*32 + l31)*1024                    \
                    + (cc_)*256 + wave*32 + hi*16;                            \
                gload_lds16(src_, (bufp_) + (wave*2 + it_)*1024);             \
            }                                                                 \
        } while (0)

    // stage V^T tile frag-linear: 32 tiles of 1KB; 8 waves stage 4 each.
    #define STAGE_V(jtb_)                                                     \
        do {                                                                  \
            _Pragma("unroll")                                                 \
            for (int it_ = 0; it_ < 4; ++it_) {                               \
                const char* src_ = (const char*)Vt                            \
                    + (size_t)(wave*32 + l31)*8192                            \
                    + (size_t)((jtb_) + it_*16 + hi*8)*2;                     \
                gload_lds16(src_, sV + (wave*4 + it_)*1024);                  \
            }                                                                 \
        } while (0)

    // phys K buffers; rotate by 1 each j (chunk g%3, 4 == 1 mod 3)
    char* q0p = smem;
    char* q1p = smem + 16384;
    char* q2p = smem + 32768;

    STAGE_K(jt0, 0, q0p);               // chunk 0 -> phys0
    STAGE_K(jt0, 1, q1p);               // chunk 1 -> phys1

    for (int j = 0; j < NJ; ++j) {
        const int jtb = jt0 + j*64;
        f32x16 s;                       // P^T acc: D[row=key][col=q]
        #pragma unroll
        for (int r = 0; r < 16; ++r) s[r] = 0.f;

        #pragma unroll
        for (int c = 0; c < 4; ++c) {
            // barrier with counted vmcnt (keep newest prefetches in flight)
            if (c == 0)      BAR_VM(2);
            else if (c == 1) BAR_VM(6);
            else if (c == 2) BAR_VM(6);
            else { if (j + 1 < NJ) BAR_VM(2); else BAR_VM(0); }

            // issue stage for chunk g+2 (lands 2 phases later)
            if (c == 0)      { STAGE_K(jtb, 2, q2p); STAGE_V(jtb); }
            else if (c == 1) STAGE_K(jtb, 3, q0p);
            else if (c == 2) { if (j + 1 < NJ) STAGE_K(jtb + 64, 0, q1p); }
            else             { if (j + 1 < NJ) STAGE_K(jtb + 64, 1, q2p); }

            // QK on chunk c (read buf: c0->q0p c1->q1p c2->q2p c3->q0p)
            const char* rbuf = (c == 0) ? q0p : (c == 1) ? q1p
                             : (c == 2) ? q2p : q0p;
            const char* kb = rbuf + wk*1024 + lane*16;
            __builtin_amdgcn_s_setprio(1);
            #pragma unroll
            for (int t = 0; t < 8; ++t) {
                bf16x8 kf = *(const bf16x8*)(kb + t*2048);
                s = __builtin_amdgcn_mfma_f32_32x32x16_bf16(kf, qf[c*8+t], s, 0, 0, 0);
            }
            __builtin_amdgcn_s_setprio(0);
        }

        // ---- softmax: in-lane (lane owns q=l31; 16 keys + hi-partner via
        //      shfl_xor(32)), then joint max across wk pair via LDS ----
        float tmax = fmaxf(fmaxf(fmaxf(s[0],s[1]),fmaxf(s[2],s[3])),
                           fmaxf(fmaxf(s[4],s[5]),fmaxf(s[6],s[7])));
        tmax = fmaxf(tmax, fmaxf(fmaxf(fmaxf(s[8],s[9]),fmaxf(s[10],s[11])),
                                 fmaxf(fmaxf(s[12],s[13]),fmaxf(s[14],s[15]))));
        tmax = fmaxf(tmax, __shfl_xor(tmax, 32));
        if (lane < 32) sSt[(wave*2 + 0)*32 + lane] = tmax;
        BAR_LGKM();                                             // exchange 1
        float tmax_o = sSt[((wave^1)*2 + 0)*32 + l31];
        const float mn = fmaxf(m_r, fmaxf(tmax, tmax_o));
        const float alpha = __expf(m_r - mn);
        float tsum = 0.f;
        #pragma unroll
        for (int r = 0; r < 16; ++r) { float pv = __expf(s[r] - mn); s[r] = pv; tsum += pv; }
        tsum += __shfl_xor(tsum, 32);

        // P -> PV A-frags in-register (cvt_pk + permlane32_swap, proven R1/R2)
        bf16x8 pf[2];
        #pragma unroll
        for (int ks = 0; ks < 2; ++ks) {
            int wA, wB, wC, wD;
            asm("v_cvt_pk_bf16_f32 %0, %1, %2" : "=v"(wA) : "v"(s[8*ks+0]), "v"(s[8*ks+1]));
            asm("v_cvt_pk_bf16_f32 %0, %1, %2" : "=v"(wB) : "v"(s[8*ks+2]), "v"(s[8*ks+3]));
            asm("v_cvt_pk_bf16_f32 %0, %1, %2" : "=v"(wC) : "v"(s[8*ks+4]), "v"(s[8*ks+5]));
            asm("v_cvt_pk_bf16_f32 %0, %1, %2" : "=v"(wD) : "v"(s[8*ks+6]), "v"(s[8*ks+7]));
            asm("v_permlane32_swap_b32 %0, %1" : "+v"(wA), "+v"(wC));
            asm("v_permlane32_swap_b32 %0, %1" : "+v"(wB), "+v"(wD));
            union { int w[4]; bf16x8 v; } u;
            u.w[0] = wA; u.w[1] = wB; u.w[2] = wC; u.w[3] = wD;
            pf[ks] = u.v;
        }
        *(bf16x8*)(sPex + (wm*4 + wk*2 + 0)*1024 + lane*16) = pf[0];
        *(bf16x8*)(sPex + (wm*4 + wk*2 + 1)*1024 + lane*16) = pf[1];
        if (lane < 32) sSt[(wave*2 + 1)*32 + lane] = tsum;
        BAR_LGKM();                                             // exchange 2
        float tsum_o = sSt[((wave^1)*2 + 1)*32 + l31];
        l_r = l_r*alpha + (tsum + tsum_o);
        m_r = mn;
        if (__any(alpha < 1.f)) {       // rescale O (alpha indexed by q-row)
            #pragma unroll
            for (int r = 0; r < 16; ++r) {
                int row = (r&3) + 8*(r>>2) + 4*hi;
                float ar = __shfl(alpha, row);
                #pragma unroll
                for (int n = 0; n < 4; ++n) o[n][r] *= ar;
            }
        }

        // ---- PV: O[dv-half wk] += P(all 64 keys) * V^T; lane-linear reads ----
        const char* vb = sV + wk*16384 + lane*16;
        const char* pb = sPex + wm*4096 + lane*16;
        __builtin_amdgcn_s_setprio(1);
        #pragma unroll
        for (int g = 0; g < 4; ++g) {
            bf16x8 pa = ((g >> 1) == wk) ? pf[g & 1]
                        : *(const bf16x8*)(pb + g*1024);
            #pragma unroll
            for (int n = 0; n < 4; ++n) {
                bf16x8 vf = *(const bf16x8*)(vb + (n*4 + g)*1024);
                o[n] = __builtin_amdgcn_mfma_f32_32x32x16_bf16(pa, vf, o[n], 0, 0, 0);
            }
        }
        __builtin_amdgcn_s_setprio(0);

        // rotate phys K bufs (next j's chunk c reads shift by 1)
        char* tp = q0p; q0p = q1p; q1p = q2p; q2p = tp;
    }
    #undef STAGE_K
    #undef STAGE_V

    // ---- epilogue: shared (m,l) across wk; disjoint dv halves -> no merge ----
    const size_t base = (size_t)split * NROWS;
    const int gr0 = q0 + wm*32;
    if (wk == 0 && lane < 32) {
        Mpart[base + gr0 + lane] = m_r;
        Lpart[base + gr0 + lane] = l_r;
    }
    #pragma unroll
    for (int r = 0; r < 16; ++r) {
        int row = (r&3) + 8*(r>>2) + 4*hi;
        float* orow = Opart + (base + gr0 + row) * (size_t)DVDIM + wk*128;
        #pragma unroll
        for (int n = 0; n < 4; ++n)
            orow[n*32 + l31] = o[n][r];
    }
}

// ---------------------------------------------------------------------------
// Combine NS split partials: out = sum_s(Os*ws) / sum_s(ls*ws), ws=exp(ms-M).
// grid = NROWS/4, block = 256: 4 rows/block, one float4 per thread. Coalesced.
// ---------------------------------------------------------------------------
__global__ void combine_splits(
    const float* __restrict__ Opart, const float* __restrict__ Mpart,
    const float* __restrict__ Lpart, float* __restrict__ out)
{
    const int row = blockIdx.x * 4 + (threadIdx.x >> 6);
    const int dv4 = (threadIdx.x & 63) * 4;
    float M = -1e30f;
    #pragma unroll
    for (int s = 0; s < NS; ++s) M = fmaxf(M, Mpart[(size_t)s*NROWS + row]);
    float denom = 0.f;
    float4 acc = make_float4(0.f, 0.f, 0.f, 0.f);
    #pragma unroll
    for (int s = 0; s < NS; ++s) {
        float w = __expf(Mpart[(size_t)s*NROWS + row] - M);
        denom += Lpart[(size_t)s*NROWS + row] * w;
        float4 ov = *(const float4*)(Opart + ((size_t)s*NROWS + row)*DVDIM + dv4);
        acc.x += ov.x*w; acc.y += ov.y*w; acc.z += ov.z*w; acc.w += ov.w*w;
    }
    float inv = 1.0f / denom;
    *(float4*)(out + (size_t)row*DVDIM + dv4)
        = make_float4(acc.x*inv, acc.y*inv, acc.z*inv, acc.w*inv);
}

extern "C" void kernel_launch(void* const* d_in, const int* in_sizes, int n_in,
                              void* d_out, int out_size, void* d_ws, size_t ws_size,
                              hipStream_t stream) {
    const float* X  = (const float*)d_in[0];   // [8,2048,512]
    const float* Y  = (const float*)d_in[1];   // [4096,512]
    const float* Z  = (const float*)d_in[2];   // [4096,512]
    const float* Wk = (const float*)d_in[3];   // [512,512]
    const float* Wv = (const float*)d_in[4];   // [256,512]
    float* out = (float*)d_out;

    // workspace layout (~38.3 MB)
    char* ws = (char*)d_ws;
    unsigned short* keyb = (unsigned short*)ws;                    // 4 MB, natural [4096][512]
    unsigned short* vtb  = (unsigned short*)(ws + (4u<<20));       // 2 MB, natural [256][4096]
    float* Opart = (float*)(ws + (6u<<20));                        // NS x 16 MB
    float* Mpart = (float*)(ws + (6u<<20) + (size_t)NS*NROWS*DVDIM*4);
    float* Lpart = Mpart + (size_t)NS*NROWS;

    // both projections, one launch
    proj_gemms<<<dim3(64, 8, 2), dim3(256), 0, stream>>>(Y, Z, Wk, Wv, keyb, vtb);
    // fused attention: 256 blocks (1/CU), 8 waves, XCD-split swizzle inside
    attn_fused<<<dim3(256), dim3(512), 0, stream>>>(
        X, keyb, vtb, Opart, Mpart, Lpart);
    // merge splits
    combine_splits<<<dim3(NROWS/4), dim3(256), 0, stream>>>(Opart, Mpart, Lpart, out);
}